// Round 6
// baseline (3555.973 us; speedup 1.0000x reference)
//
#include <hip/hip_runtime.h>

#define DD 800
#define HH 800
#define BB 64
#define TT 48
#define N3H 2400
#define VV 32000
#define MR (TT*BB)   // 3072 rows, time-major (t*BB + b)
#define NBLK 25      // scan blocks: 25 x 32 H-columns

typedef __attribute__((ext_vector_type(8))) short bf16x8;
typedef __attribute__((ext_vector_type(4))) float f32x4;
typedef __attribute__((ext_vector_type(4))) float float4v;
typedef __attribute__((address_space(1))) const unsigned int as1_uint;
typedef __attribute__((address_space(3))) unsigned int as3_uint;

__device__ __forceinline__ short f2bf(float f) {
  unsigned int u = __builtin_bit_cast(unsigned int, f);
  u = (u + 0x7fffu + ((u >> 16) & 1u)) >> 16;
  return (short)(unsigned short)u;
}

__device__ __forceinline__ void gload16(const void* g, void* l) {
  __builtin_amdgcn_global_load_lds((as1_uint*)g, (as3_uint*)l, 16, 0, 0);
}

// device-coherent 16B load/store: bypass L1(sc0)+L2(sc1), coherent at IC.
__device__ __forceinline__ bf16x8 load16_cc(const short* p) {
  bf16x8 v;
  asm volatile("global_load_dwordx4 %0, %1, off sc0 sc1" : "=v"(v) : "v"(p));
  return v;
}
__device__ __forceinline__ void store16_cc(short* p, bf16x8 v) {
  asm volatile("global_store_dwordx4 %0, %1, off sc0 sc1" :: "v"(p), "v"(v));
}

// ---------------- transpose + cast fp32 [K][N] -> bf16 [N][K] ----------------
__global__ void k_cast_transpose(const float* __restrict__ src, short* __restrict__ dst,
                                 int K, int N) {
  __shared__ float tile[32][33];
  int n0 = blockIdx.x * 32, k0 = blockIdx.y * 32;
  int tx = threadIdx.x, ty = threadIdx.y;   // (32,8)
#pragma unroll
  for (int i = 0; i < 4; ++i) {
    int k = k0 + ty + i * 8, n = n0 + tx;
    if (k < K && n < N) tile[ty + i * 8][tx] = src[(size_t)k * N + n];
  }
  __syncthreads();
#pragma unroll
  for (int i = 0; i < 4; ++i) {
    int n = n0 + ty + i * 8, k = k0 + tx;
    if (n < N && k < K) dst[(size_t)n * K + k] = f2bf(tile[tx][ty + i * 8]);
  }
}

// ---------------- gather embedding rows -> bf16, time-major ----------------
__global__ void k_gather(const int* __restrict__ ids, const float* __restrict__ emb,
                         short* __restrict__ out) {
  int r = blockIdx.x;            // r = t*BB + b
  int t = r >> 6, b = r & 63;
  int id = ids[b * TT + t];
  int i = threadIdx.x;
  if (i < 100) {
    const float* s = emb + (size_t)id * DD + i * 8;
    float4v v0 = *(const float4v*)s;
    float4v v1 = *(const float4v*)(s + 4);
    bf16x8 o;
    o[0] = f2bf(v0[0]); o[1] = f2bf(v0[1]); o[2] = f2bf(v0[2]); o[3] = f2bf(v0[3]);
    o[4] = f2bf(v1[0]); o[5] = f2bf(v1[1]); o[6] = f2bf(v1[2]); o[7] = f2bf(v1[3]);
    *(bf16x8*)(out + (size_t)r * DD + i * 8) = o;
  }
}

// ---------------- generic bf16 GEMM: C = A[M,K] * BT[N,K]^T + bias ----------------
// EPI 0: fp32 store (xg).  EPI 1: relu -> bf16 (fe).
// EPI 2: exp(v+bias), row-permuted store + per-wave row partial sums into Pp.
template <int EPI>
__global__ __launch_bounds__(256) void k_gemm(const short* __restrict__ A,
                                              const short* __restrict__ BT,
                                              const float* __restrict__ bias,
                                              float* __restrict__ Cf,
                                              short* __restrict__ Cb,
                                              float* __restrict__ Pp,
                                              int N, int K, int ldc) {
  __shared__ short lA[128 * 32];
  __shared__ short lB[128 * 32];
  const int tid = threadIdx.x, wid = tid >> 6, lane = tid & 63;
  const int m0 = blockIdx.y * 128, n0 = blockIdx.x * 128;
  const int wr = wid >> 1, wc = wid & 1;
  f32x4 acc[4][4] = {};
  for (int kt = 0; kt < K / 32; ++kt) {
    const int kb = kt * 32;
#pragma unroll
    for (int rr = 0; rr < 2; ++rr) {
      int s = rr * 256 + tid;
      gload16(A + (size_t)(m0 + (s >> 2)) * K + kb + (s & 3) * 8, (char*)lA + s * 16);
      gload16(BT + (size_t)(n0 + (s >> 2)) * K + kb + (s & 3) * 8, (char*)lB + s * 16);
    }
    __syncthreads();
    bf16x8 af[4], bfr[4];
#pragma unroll
    for (int i = 0; i < 4; ++i)
      af[i] = *(const bf16x8*)(lA + (wr * 64 + i * 16 + (lane & 15)) * 32 + (lane >> 4) * 8);
#pragma unroll
    for (int j = 0; j < 4; ++j)
      bfr[j] = *(const bf16x8*)(lB + (wc * 64 + j * 16 + (lane & 15)) * 32 + (lane >> 4) * 8);
#pragma unroll
    for (int i = 0; i < 4; ++i)
#pragma unroll
      for (int j = 0; j < 4; ++j)
        acc[i][j] = __builtin_amdgcn_mfma_f32_16x16x32_bf16(af[i], bfr[j], acc[i][j], 0, 0, 0);
    __syncthreads();
  }
  const int hi = lane >> 4, ccol = lane & 15;
  if (EPI == 2) {
#pragma unroll
    for (int i = 0; i < 4; ++i) {
      int row = m0 + wr * 64 + i * 16 + hi * 4;
#pragma unroll
      for (int rg = 0; rg < 4; ++rg) {
        int r = row + rg;
        int orow = (r & 63) * TT + (r >> 6);   // (t,b) -> (b,t)
        float part = 0.f;
#pragma unroll
        for (int j = 0; j < 4; ++j) {
          int col = n0 + wc * 64 + j * 16 + ccol;
          float v = __expf(acc[i][j][rg] + bias[col]);
          part += v;
          Cf[(size_t)orow * ldc + col] = v;
        }
#pragma unroll
        for (int mm = 1; mm < 16; mm <<= 1) part += __shfl_xor(part, mm);
        if (ccol == 0) Pp[(size_t)orow * 512 + blockIdx.x * 2 + wc] = part;
      }
    }
  } else {
#pragma unroll
    for (int i = 0; i < 4; ++i) {
      int row = m0 + wr * 64 + i * 16 + hi * 4;
#pragma unroll
      for (int j = 0; j < 4; ++j) {
        int col = n0 + wc * 64 + j * 16 + ccol;
        if (col >= N) continue;
        float bv = bias ? bias[col] : 0.f;
#pragma unroll
        for (int rg = 0; rg < 4; ++rg) {
          int r = row + rg;
          float v = acc[i][j][rg] + bv;
          if (EPI == 0) Cf[(size_t)r * ldc + col] = v;
          else          Cb[(size_t)r * ldc + col] = f2bf(v < 0.f ? 0.f : v);
        }
      }
    }
  }
}

// ------- grid barrier: flag-store arrive + 25-lane vector-load poll -------
// FENCE 0: none.  1: full release/acquire pair.  2: release-only (no buffer_inv).
template <int FENCE>
__device__ __forceinline__ void bar_sync(int* flags, int ep, int tid) {
  asm volatile("s_waitcnt vmcnt(0)" ::: "memory");   // per-wave store drain
  __syncthreads();
  if (tid == 0) {
    if (FENCE >= 1) __builtin_amdgcn_fence(__ATOMIC_RELEASE, "agent");
    __hip_atomic_store(&flags[blockIdx.x * 32], ep, __ATOMIC_RELAXED, __HIP_MEMORY_SCOPE_AGENT);
  }
  if (tid < 64) {
    bool ok;
    do {
      int v = ep;
      if (tid < NBLK)
        v = __hip_atomic_load(&flags[tid * 32], __ATOMIC_RELAXED, __HIP_MEMORY_SCOPE_AGENT);
      ok = __all(v - ep >= 0);
      if (!ok) __builtin_amdgcn_s_sleep(1);
    } while (!ok);
    if (FENCE == 1) __builtin_amdgcn_fence(__ATOMIC_ACQUIRE, "agent");
  }
  __syncthreads();
}

// ---------------- persistent GRU scan (one layer, 48 steps) ----------------
// Variants (h-exchange path):
//  V0: cached hB loads, NT per-short stores, barrier-2 full fence pair   (R5 anchor)
//  V1: sc0sc1 dwordx4 loads, LDS-coalesced sc0sc1 dwordx4 stores, fence-free
//  V2: sc0sc1 dwordx4 loads, NT per-short stores, release-only fence
//  V3: sc0sc1 dwordx4 loads, per-short agent atomic stores, fence-free   (R4 store path)
template <int V>
__global__ __launch_bounds__(512, 1) void k_scan(const float* __restrict__ xg,
                                                 const short* __restrict__ UT,
                                                 const float* __restrict__ br,
                                                 float* __restrict__ hF,
                                                 short* __restrict__ hB,
                                                 short* __restrict__ gOut,
                                                 float* __restrict__ Spart,
                                                 int* flags, int ep0) {
  __shared__ short uT[96 * 808];     // [gate*32+lc][800], stride 808 (16B aligned)
  __shared__ float sSum[128];
  __shared__ short hTile[64 * 32];   // V1 staging for coalesced h stores
  const int tid = threadIdx.x, wid = tid >> 6, lane = tid & 63;
  const int bid = blockIdx.x, c0 = bid * 32;
  const int rt = wid & 3, ch = wid >> 2;
  for (int idx = tid; idx < 96 * 100; idx += 512) {
    int rr = idx / 100, chk = idx % 100;
    int grow = (rr >> 5) * HH + c0 + (rr & 31);
    *(bf16x8*)(uT + rr * 808 + chk * 8) = *(const bf16x8*)(UT + (size_t)grow * HH + chk * 8);
  }
  const int hi = lane >> 4;
  const int ccol = lane & 15;
  const int crow = rt * 16 + hi * 4;          // C-layout row base
  const int gcol = c0 + ch * 16 + ccol;       // global H column
  const int arow = rt * 16 + ccol;            // A-operand row
  const short* uz = uT + (0 * 32 + ch * 16 + ccol) * 808;
  const short* ur = uT + (1 * 32 + ch * 16 + ccol) * 808;
  const short* uh = uT + (2 * 32 + ch * 16 + ccol) * 808;
  f32x4 hfr;
#pragma unroll
  for (int rg = 0; rg < 4; ++rg) hfr[rg] = hF[(crow + rg) * HH + gcol];
  const float brz = br[gcol], brr = br[HH + gcol], brh = br[2 * HH + gcol];
  int ep = ep0;
  float xzv[4], xrv[4], xhv[4];
#pragma unroll
  for (int rg = 0; rg < 4; ++rg) {
    const float* xrow = xg + ((size_t)(crow + rg)) * N3H;
    xzv[rg] = xrow[gcol];
    xrv[rg] = xrow[HH + gcol];
    xhv[rg] = xrow[2 * HH + gcol];
  }
  __syncthreads();

#pragma unroll 1
  for (int t = 0; t < TT; ++t) {
    // ---- phase 1: load hB, MFMA, exp, partial row sums -> Spart (agent atomics) ----
    bf16x8 areg[25];
    if (V == 0) {
#pragma unroll
      for (int kt = 0; kt < 25; ++kt)
        areg[kt] = *(const bf16x8*)(hB + arow * HH + kt * 32 + hi * 8);
    } else {
#pragma unroll
      for (int kt = 0; kt < 25; ++kt)
        areg[kt] = load16_cc(hB + arow * HH + kt * 32 + hi * 8);
      asm volatile("s_waitcnt vmcnt(0)" ::: "memory");
      __builtin_amdgcn_sched_barrier(0);
    }
    f32x4 az = {}, ar = {}, ah = {};
#pragma unroll
    for (int kt = 0; kt < 25; ++kt) {
      const int o = kt * 32 + hi * 8;
      az = __builtin_amdgcn_mfma_f32_16x16x32_bf16(areg[kt], *(const bf16x8*)(uz + o), az, 0, 0, 0);
      ar = __builtin_amdgcn_mfma_f32_16x16x32_bf16(areg[kt], *(const bf16x8*)(ur + o), ar, 0, 0, 0);
      ah = __builtin_amdgcn_mfma_f32_16x16x32_bf16(areg[kt], *(const bf16x8*)(uh + o), ah, 0, 0, 0);
    }
    float ez[4], er[4], rh[4];
#pragma unroll
    for (int rg = 0; rg < 4; ++rg) {
      ez[rg] = __expf(xzv[rg] + az[rg] + brz);
      er[rg] = __expf(xrv[rg] + ar[rg] + brr);
      rh[rg] = ah[rg] + brh;
      float s1 = ez[rg], s2 = er[rg];
#pragma unroll
      for (int mm = 1; mm < 16; mm <<= 1) {
        s1 += __shfl_xor(s1, mm);
        s2 += __shfl_xor(s2, mm);
      }
      if (ccol == 0) {
        const int slot = bid * 2 + ch;
        __hip_atomic_store(&Spart[slot * 128 + crow + rg], s1, __ATOMIC_RELAXED, __HIP_MEMORY_SCOPE_AGENT);
        __hip_atomic_store(&Spart[slot * 128 + 64 + crow + rg], s2, __ATOMIC_RELAXED, __HIP_MEMORY_SCOPE_AGENT);
      }
    }
    bar_sync<0>(flags, ++ep, tid);     // Spart is IC-coherent: fence-free
    // ---- phase 2: reduce partials, gates, update h; prefetch next xg ----
    if (tid < 128) {
      float s = 0.f;
#pragma unroll
      for (int sl = 0; sl < 2 * NBLK; ++sl)
        s += __hip_atomic_load(&Spart[sl * 128 + tid], __ATOMIC_RELAXED, __HIP_MEMORY_SCOPE_AGENT);
      sSum[tid] = s;
    }
    __syncthreads();
#pragma unroll
    for (int rg = 0; rg < 4; ++rg) {
      int r = crow + rg;
      float z = ez[rg] / sSum[r];
      float rr2 = er[rg] / sSum[64 + r];
      float hh = tanhf(xhv[rg] + rr2 * rh[rg]);
      float hn = z * hfr[rg] + (1.f - z) * hh;
      hfr[rg] = hn;
      short hb = f2bf(hn);
      if (V == 0 || V == 2) {
        __builtin_nontemporal_store(hb, &hB[r * HH + gcol]);
      } else if (V == 1) {
        hTile[r * 32 + ch * 16 + ccol] = hb;
      } else {
        __hip_atomic_store(&hB[r * HH + gcol], hb, __ATOMIC_RELAXED, __HIP_MEMORY_SCOPE_AGENT);
      }
      if (gOut) __builtin_nontemporal_store(hb, &gOut[((size_t)t * BB + r) * HH + gcol]);
    }
    if (V == 1) {
      __syncthreads();
      if (tid < 256) {
        int row = tid >> 2, seg = tid & 3;
        bf16x8 v = *(const bf16x8*)(hTile + row * 32 + seg * 8);
        store16_cc(hB + row * HH + c0 + seg * 8, v);
      }
    }
    if (t + 1 < TT) {
#pragma unroll
      for (int rg = 0; rg < 4; ++rg) {
        const float* xrow = xg + ((size_t)(t + 1) * BB + crow + rg) * N3H;
        xzv[rg] = xrow[gcol];
        xrv[rg] = xrow[HH + gcol];
        xhv[rg] = xrow[2 * HH + gcol];
      }
    }
    if (V == 0)      bar_sync<1>(flags, ++ep, tid);   // full fence pair
    else if (V == 2) bar_sync<2>(flags, ++ep, tid);   // release-only
    else             bar_sync<0>(flags, ++ep, tid);   // fence-free
  }
#pragma unroll
  for (int rg = 0; rg < 4; ++rg) hF[(crow + rg) * HH + gcol] = hfr[rg];
}

// -------- normalize pass: sum 500 per-row partials, scale row (exp already stored) --------
__global__ __launch_bounds__(256) void k_softmax(float* __restrict__ out,
                                                 const float* __restrict__ Pp) {
  float* row = out + (size_t)blockIdx.x * VV;
  const float* pp = Pp + (size_t)blockIdx.x * 512;
  const int tid = threadIdx.x;
  __shared__ float red[4];
  float sum = 0.f;
  for (int i = tid; i < 500; i += 256) sum += pp[i];
#pragma unroll
  for (int s = 32; s >= 1; s >>= 1) sum += __shfl_xor(sum, s);
  if ((tid & 63) == 0) red[tid >> 6] = sum;
  __syncthreads();
  float inv = 1.f / (red[0] + red[1] + red[2] + red[3]);
  for (int i = tid * 4; i < VV; i += 1024) {
    float4v v = *(const float4v*)(row + i);
    v[0] *= inv; v[1] *= inv; v[2] *= inv; v[3] *= inv;
    *(float4v*)(row + i) = v;
  }
}

extern "C" void kernel_launch(void* const* d_in, const int* in_sizes, int n_in,
                              void* d_out, int out_size, void* d_ws, size_t ws_size,
                              hipStream_t stream) {
  (void)in_sizes; (void)n_in; (void)out_size; (void)ws_size;
  const int*   enc  = (const int*)d_in[0];
  const int*   dec  = (const int*)d_in[1];
  const float* embF = (const float*)d_in[2];
  const float* Wd1  = (const float*)d_in[3];
  const float* bd1  = (const float*)d_in[4];
  const float* Wf1  = (const float*)d_in[5];
  const float* Uf1  = (const float*)d_in[6];
  const float* bf1  = (const float*)d_in[7];
  const float* Wf2  = (const float*)d_in[8];
  const float* Uf2  = (const float*)d_in[9];
  const float* bf2  = (const float*)d_in[10];
  const float* embE = (const float*)d_in[11];
  const float* We1  = (const float*)d_in[12];
  const float* Ue1  = (const float*)d_in[13];
  const float* be1  = (const float*)d_in[14];
  const float* We2  = (const float*)d_in[15];
  const float* Ue2  = (const float*)d_in[16];
  const float* be2  = (const float*)d_in[17];
  const float* Wout = (const float*)d_in[18];
  const float* bout = (const float*)d_in[19];

  char* p = (char*)d_ws;
  auto alloc = [&](size_t bytes) { char* r = p; p += (bytes + 255) & ~(size_t)255; return r; };
  short* WdT = (short*)alloc((size_t)896 * 800 * 2);
  short* WTb[4]; short* UTb[4];
  for (int i = 0; i < 4; ++i) {
    WTb[i] = (short*)alloc((size_t)2432 * 800 * 2);
    UTb[i] = (short*)alloc((size_t)2400 * 800 * 2);
  }
  short* WoT = (short*)alloc((size_t)VV * 800 * 2);
  short* feA = (short*)alloc((size_t)MR * DD * 2);
  short* fe  = (short*)alloc((size_t)MR * DD * 2);
  short* ee  = (short*)alloc((size_t)MR * DD * 2);
  short* g1  = (short*)alloc((size_t)MR * HH * 2);
  short* e1  = (short*)alloc((size_t)MR * HH * 2);
  short* e2  = (short*)alloc((size_t)MR * HH * 2);
  float* xg  = (float*)alloc((size_t)MR * N3H * 4);
  float* Ppart = (float*)alloc((size_t)MR * 512 * 4);
  float* Spart = (float*)alloc((size_t)50 * 128 * 4);
  // --- zeroed-at-launch region: hF .. flags ---
  float* hF  = (float*)alloc((size_t)BB * HH * 4);
  short* hB  = (short*)alloc((size_t)BB * HH * 2);
  int* flags = (int*)alloc((size_t)NBLK * 32 * 4);

  size_t tail = (char*)(flags + NBLK * 32) - (char*)hF;
  hipMemsetAsync(hF, 0, tail, stream);

  dim3 tb(32, 8);
  k_cast_transpose<<<dim3(25, 25), tb, 0, stream>>>(Wd1, WdT, 800, 800);
  const float* Ws[4] = {Wf1, Wf2, We1, We2};
  const float* Us[4] = {Uf1, Uf2, Ue1, Ue2};
  for (int i = 0; i < 4; ++i) {
    k_cast_transpose<<<dim3(75, 25), tb, 0, stream>>>(Ws[i], WTb[i], 800, 2400);
    k_cast_transpose<<<dim3(75, 25), tb, 0, stream>>>(Us[i], UTb[i], 800, 2400);
  }
  k_cast_transpose<<<dim3(1000, 25), tb, 0, stream>>>(Wout, WoT, 800, VV);
  k_gather<<<MR, 128, 0, stream>>>(enc, embF, feA);
  k_gather<<<MR, 128, 0, stream>>>(dec, embE, ee);
  // fe = relu(feA @ Wd1 + bd1)  -> bf16
  k_gemm<1><<<dim3(7, 24), 256, 0, stream>>>(feA, WdT, bd1, nullptr, fe, nullptr, 800, 800, 800);

  const float* bs[4] = {bf1, bf2, be1, be2};
  const short* Xs[4] = {fe, g1, ee, e1};
  short* Gs[4] = {g1, nullptr, e1, e2};
  // layer -> variant A/B/C/D test (all correct; only sync strategy differs)
  k_gemm<0><<<dim3(19, 24), 256, 0, stream>>>(Xs[0], WTb[0], bs[0], xg, nullptr, nullptr, N3H, 800, N3H);
  k_scan<0><<<NBLK, 512, 0, stream>>>(xg, UTb[0], bs[0] + N3H, hF, hB, Gs[0], Spart, flags, 0 * 2 * TT);
  k_gemm<0><<<dim3(19, 24), 256, 0, stream>>>(Xs[1], WTb[1], bs[1], xg, nullptr, nullptr, N3H, 800, N3H);
  k_scan<1><<<NBLK, 512, 0, stream>>>(xg, UTb[1], bs[1] + N3H, hF, hB, Gs[1], Spart, flags, 1 * 2 * TT);
  k_gemm<0><<<dim3(19, 24), 256, 0, stream>>>(Xs[2], WTb[2], bs[2], xg, nullptr, nullptr, N3H, 800, N3H);
  k_scan<2><<<NBLK, 512, 0, stream>>>(xg, UTb[2], bs[2] + N3H, hF, hB, Gs[2], Spart, flags, 2 * 2 * TT);
  k_gemm<0><<<dim3(19, 24), 256, 0, stream>>>(Xs[3], WTb[3], bs[3], xg, nullptr, nullptr, N3H, 800, N3H);
  k_scan<3><<<NBLK, 512, 0, stream>>>(xg, UTb[3], bs[3] + N3H, hF, hB, Gs[3], Spart, flags, 3 * 2 * TT);
  // out = exp(e2 @ Wout + bout) -> d_out (row-permuted to [B,T,V]) + row partials
  k_gemm<2><<<dim3(250, 24), 256, 0, stream>>>(e2, WoT, bout, (float*)d_out, nullptr, Ppart, VV, 800, VV);
  k_softmax<<<MR, 256, 0, stream>>>((float*)d_out, Ppart);
}

// Round 7
// 2524.718 us; speedup vs baseline: 1.4085x; 1.4085x over previous
//
#include <hip/hip_runtime.h>

#define DD 800
#define HH 800
#define BB 64
#define TT 48
#define N3H 2400
#define VV 32000
#define MR (TT*BB)   // 3072 rows, time-major (t*BB + b)
#define NBLK 25      // scan blocks: 25 x 32 H-columns

typedef __attribute__((ext_vector_type(8))) short bf16x8;
typedef __attribute__((ext_vector_type(4))) float f32x4;
typedef __attribute__((ext_vector_type(4))) float float4v;
typedef __attribute__((address_space(1))) const unsigned int as1_uint;
typedef __attribute__((address_space(3))) unsigned int as3_uint;

__device__ __forceinline__ short f2bf(float f) {
  unsigned int u = __builtin_bit_cast(unsigned int, f);
  u = (u + 0x7fffu + ((u >> 16) & 1u)) >> 16;
  return (short)(unsigned short)u;
}

__device__ __forceinline__ void gload16(const void* g, void* l) {
  __builtin_amdgcn_global_load_lds((as1_uint*)g, (as3_uint*)l, 16, 0, 0);
}

// device-coherent 16B store: write-through to IC (visible to all XCDs after vmcnt drain).
__device__ __forceinline__ void store16_cc(short* p, bf16x8 v) {
  asm volatile("global_store_dwordx4 %0, %1, off sc0 sc1" :: "v"(p), "v"(v));
}

// ---------------- transpose + cast fp32 [K][N] -> bf16 [N][K] ----------------
__global__ void k_cast_transpose(const float* __restrict__ src, short* __restrict__ dst,
                                 int K, int N) {
  __shared__ float tile[32][33];
  int n0 = blockIdx.x * 32, k0 = blockIdx.y * 32;
  int tx = threadIdx.x, ty = threadIdx.y;   // (32,8)
#pragma unroll
  for (int i = 0; i < 4; ++i) {
    int k = k0 + ty + i * 8, n = n0 + tx;
    if (k < K && n < N) tile[ty + i * 8][tx] = src[(size_t)k * N + n];
  }
  __syncthreads();
#pragma unroll
  for (int i = 0; i < 4; ++i) {
    int n = n0 + ty + i * 8, k = k0 + tx;
    if (n < N && k < K) dst[(size_t)n * K + k] = f2bf(tile[tx][ty + i * 8]);
  }
}

// ---------------- gather embedding rows -> bf16, time-major ----------------
__global__ void k_gather(const int* __restrict__ ids, const float* __restrict__ emb,
                         short* __restrict__ out) {
  int r = blockIdx.x;            // r = t*BB + b
  int t = r >> 6, b = r & 63;
  int id = ids[b * TT + t];
  int i = threadIdx.x;
  if (i < 100) {
    const float* s = emb + (size_t)id * DD + i * 8;
    float4v v0 = *(const float4v*)s;
    float4v v1 = *(const float4v*)(s + 4);
    bf16x8 o;
    o[0] = f2bf(v0[0]); o[1] = f2bf(v0[1]); o[2] = f2bf(v0[2]); o[3] = f2bf(v0[3]);
    o[4] = f2bf(v1[0]); o[5] = f2bf(v1[1]); o[6] = f2bf(v1[2]); o[7] = f2bf(v1[3]);
    *(bf16x8*)(out + (size_t)r * DD + i * 8) = o;
  }
}

// ---------------- generic bf16 GEMM: C = A[M,K] * BT[N,K]^T + bias ----------------
// EPI 0: fp32 store (xg).  EPI 1: relu -> bf16 (fe).
// EPI 2: exp(v+bias), row-permuted store + per-wave row partial sums into Pp.
template <int EPI>
__global__ __launch_bounds__(256) void k_gemm(const short* __restrict__ A,
                                              const short* __restrict__ BT,
                                              const float* __restrict__ bias,
                                              float* __restrict__ Cf,
                                              short* __restrict__ Cb,
                                              float* __restrict__ Pp,
                                              int N, int K, int ldc) {
  __shared__ short lA[128 * 32];
  __shared__ short lB[128 * 32];
  const int tid = threadIdx.x, wid = tid >> 6, lane = tid & 63;
  const int m0 = blockIdx.y * 128, n0 = blockIdx.x * 128;
  const int wr = wid >> 1, wc = wid & 1;
  f32x4 acc[4][4] = {};
  for (int kt = 0; kt < K / 32; ++kt) {
    const int kb = kt * 32;
#pragma unroll
    for (int rr = 0; rr < 2; ++rr) {
      int s = rr * 256 + tid;
      gload16(A + (size_t)(m0 + (s >> 2)) * K + kb + (s & 3) * 8, (char*)lA + s * 16);
      gload16(BT + (size_t)(n0 + (s >> 2)) * K + kb + (s & 3) * 8, (char*)lB + s * 16);
    }
    __syncthreads();
    bf16x8 af[4], bfr[4];
#pragma unroll
    for (int i = 0; i < 4; ++i)
      af[i] = *(const bf16x8*)(lA + (wr * 64 + i * 16 + (lane & 15)) * 32 + (lane >> 4) * 8);
#pragma unroll
    for (int j = 0; j < 4; ++j)
      bfr[j] = *(const bf16x8*)(lB + (wc * 64 + j * 16 + (lane & 15)) * 32 + (lane >> 4) * 8);
#pragma unroll
    for (int i = 0; i < 4; ++i)
#pragma unroll
      for (int j = 0; j < 4; ++j)
        acc[i][j] = __builtin_amdgcn_mfma_f32_16x16x32_bf16(af[i], bfr[j], acc[i][j], 0, 0, 0);
    __syncthreads();
  }
  const int hi = lane >> 4, ccol = lane & 15;
  if (EPI == 2) {
#pragma unroll
    for (int i = 0; i < 4; ++i) {
      int row = m0 + wr * 64 + i * 16 + hi * 4;
#pragma unroll
      for (int rg = 0; rg < 4; ++rg) {
        int r = row + rg;
        int orow = (r & 63) * TT + (r >> 6);   // (t,b) -> (b,t)
        float part = 0.f;
#pragma unroll
        for (int j = 0; j < 4; ++j) {
          int col = n0 + wc * 64 + j * 16 + ccol;
          float v = __expf(acc[i][j][rg] + bias[col]);
          part += v;
          Cf[(size_t)orow * ldc + col] = v;
        }
#pragma unroll
        for (int mm = 1; mm < 16; mm <<= 1) part += __shfl_xor(part, mm);
        if (ccol == 0) Pp[(size_t)orow * 512 + blockIdx.x * 2 + wc] = part;
      }
    }
  } else {
#pragma unroll
    for (int i = 0; i < 4; ++i) {
      int row = m0 + wr * 64 + i * 16 + hi * 4;
#pragma unroll
      for (int j = 0; j < 4; ++j) {
        int col = n0 + wc * 64 + j * 16 + ccol;
        if (col >= N) continue;
        float bv = bias ? bias[col] : 0.f;
#pragma unroll
        for (int rg = 0; rg < 4; ++rg) {
          int r = row + rg;
          float v = acc[i][j][rg] + bv;
          if (EPI == 0) Cf[(size_t)r * ldc + col] = v;
          else          Cb[(size_t)r * ldc + col] = f2bf(v < 0.f ? 0.f : v);
        }
      }
    }
  }
}

// ------- grid barrier: FENCE-FREE flag-store arrive + 25-lane vector-load poll -------
// All cross-block payloads travel via sc0sc1 (IC write-through) stores; readers use
// plain cached loads at never-cached addresses. vmcnt(0) drain before arrive gives
// release at the IC coherence point; causality at IC gives acquire.
__device__ __forceinline__ void bar_sync(int* flags, int ep, int tid) {
  asm volatile("s_waitcnt vmcnt(0)" ::: "memory");   // per-wave store drain
  __syncthreads();
  if (tid == 0)
    __hip_atomic_store(&flags[blockIdx.x * 32], ep, __ATOMIC_RELAXED, __HIP_MEMORY_SCOPE_AGENT);
  if (tid < 64) {
    bool ok;
    do {
      int v = ep;
      if (tid < NBLK)
        v = __hip_atomic_load(&flags[tid * 32], __ATOMIC_RELAXED, __HIP_MEMORY_SCOPE_AGENT);
      ok = __all(v - ep >= 0);
      if (!ok) __builtin_amdgcn_s_sleep(1);
    } while (!ok);
  }
  __syncthreads();
}

// ---------------- persistent GRU scan (one layer, 48 steps) ----------------
// 25 blocks x 512 threads; block owns 32 H-columns; U^T stripe in LDS; h fp32 in
// registers. h exchange: per-step buffer hSeq[t] (never-cached addresses) written
// via LDS-coalesced sc0sc1 16B stores, read via plain cached loads. No fences.
__global__ __launch_bounds__(512, 1) void k_scan(const float* __restrict__ xg,
                                                 const short* __restrict__ UT,
                                                 const float* __restrict__ br,
                                                 float* __restrict__ hF,
                                                 const short* __restrict__ hInit,
                                                 short* __restrict__ hSeq,
                                                 float* __restrict__ Spart,
                                                 int* flags, int ep0) {
  __shared__ short uT[96 * 808];     // [gate*32+lc][800], stride 808 (16B aligned)
  __shared__ float sSum[128];
  __shared__ short hTile[64 * 32];   // staging for coalesced h stores
  const int tid = threadIdx.x, wid = tid >> 6, lane = tid & 63;
  const int bid = blockIdx.x, c0 = bid * 32;
  const int rt = wid & 3, ch = wid >> 2;
  // stage U^T stripe: LDS row rr = g*32 + lc  <->  UT row g*800 + c0 + lc
  for (int idx = tid; idx < 96 * 100; idx += 512) {
    int rr = idx / 100, chk = idx % 100;
    int grow = (rr >> 5) * HH + c0 + (rr & 31);
    *(bf16x8*)(uT + rr * 808 + chk * 8) = *(const bf16x8*)(UT + (size_t)grow * HH + chk * 8);
  }
  const int hi = lane >> 4;
  const int ccol = lane & 15;
  const int crow = rt * 16 + hi * 4;          // C-layout row base
  const int gcol = c0 + ch * 16 + ccol;       // global H column
  const int arow = rt * 16 + ccol;            // A-operand row
  const short* uz = uT + (0 * 32 + ch * 16 + ccol) * 808;
  const short* ur = uT + (1 * 32 + ch * 16 + ccol) * 808;
  const short* uh = uT + (2 * 32 + ch * 16 + ccol) * 808;
  f32x4 hfr;
#pragma unroll
  for (int rg = 0; rg < 4; ++rg) hfr[rg] = hF[(crow + rg) * HH + gcol];
  const float brz = br[gcol], brr = br[HH + gcol], brh = br[2 * HH + gcol];
  int ep = ep0;
  float xzv[4], xrv[4], xhv[4];
#pragma unroll
  for (int rg = 0; rg < 4; ++rg) {
    const float* xrow = xg + ((size_t)(crow + rg)) * N3H;
    xzv[rg] = xrow[gcol];
    xrv[rg] = xrow[HH + gcol];
    xhv[rg] = xrow[2 * HH + gcol];
  }
  __syncthreads();

#pragma unroll 1
  for (int t = 0; t < TT; ++t) {
    // ---- phase 1: cached loads of h(t-1) (fresh addresses), MFMA, exp, partials ----
    const short* hPrev = (t == 0) ? hInit : hSeq + (size_t)(t - 1) * BB * HH;
    bf16x8 areg[25];
#pragma unroll
    for (int kt = 0; kt < 25; ++kt)
      areg[kt] = *(const bf16x8*)(hPrev + arow * HH + kt * 32 + hi * 8);
    f32x4 az = {}, ar = {}, ah = {};
#pragma unroll
    for (int kt = 0; kt < 25; ++kt) {
      const int o = kt * 32 + hi * 8;
      az = __builtin_amdgcn_mfma_f32_16x16x32_bf16(areg[kt], *(const bf16x8*)(uz + o), az, 0, 0, 0);
      ar = __builtin_amdgcn_mfma_f32_16x16x32_bf16(areg[kt], *(const bf16x8*)(ur + o), ar, 0, 0, 0);
      ah = __builtin_amdgcn_mfma_f32_16x16x32_bf16(areg[kt], *(const bf16x8*)(uh + o), ah, 0, 0, 0);
    }
    float ez[4], er[4], rh[4];
    float* sb = Spart + (size_t)t * 50 * 128;
#pragma unroll
    for (int rg = 0; rg < 4; ++rg) {
      ez[rg] = __expf(xzv[rg] + az[rg] + brz);
      er[rg] = __expf(xrv[rg] + ar[rg] + brr);
      rh[rg] = ah[rg] + brh;
      float s1 = ez[rg], s2 = er[rg];
#pragma unroll
      for (int mm = 1; mm < 16; mm <<= 1) {
        s1 += __shfl_xor(s1, mm);
        s2 += __shfl_xor(s2, mm);
      }
      if (ccol == 0) {
        const int slot = bid * 2 + ch;
        __hip_atomic_store(&sb[slot * 128 + crow + rg], s1, __ATOMIC_RELAXED, __HIP_MEMORY_SCOPE_AGENT);
        __hip_atomic_store(&sb[slot * 128 + 64 + crow + rg], s2, __ATOMIC_RELAXED, __HIP_MEMORY_SCOPE_AGENT);
      }
    }
    bar_sync(flags, ++ep, tid);
    // ---- phase 2: reduce partials, gates, h -> hTile -> coalesced sc1 store ----
    if (tid < 128) {
      float s = 0.f;
#pragma unroll
      for (int sl = 0; sl < 2 * NBLK; ++sl)
        s += __hip_atomic_load(&sb[sl * 128 + tid], __ATOMIC_RELAXED, __HIP_MEMORY_SCOPE_AGENT);
      sSum[tid] = s;
    }
    __syncthreads();
#pragma unroll
    for (int rg = 0; rg < 4; ++rg) {
      int r = crow + rg;
      float z = ez[rg] / sSum[r];
      float rr2 = er[rg] / sSum[64 + r];
      float hh = tanhf(xhv[rg] + rr2 * rh[rg]);
      float hn = z * hfr[rg] + (1.f - z) * hh;
      hfr[rg] = hn;
      hTile[r * 32 + ch * 16 + ccol] = f2bf(hn);
    }
    __syncthreads();
    short* hCur = hSeq + (size_t)t * BB * HH;
    if (tid < 256) {
      int row = tid >> 2, seg = tid & 3;
      store16_cc(hCur + row * HH + c0 + seg * 8, *(const bf16x8*)(hTile + row * 32 + seg * 8));
    }
    if (t + 1 < TT) {
#pragma unroll
      for (int rg = 0; rg < 4; ++rg) {
        const float* xrow = xg + ((size_t)(t + 1) * BB + crow + rg) * N3H;
        xzv[rg] = xrow[gcol];
        xrv[rg] = xrow[HH + gcol];
        xhv[rg] = xrow[2 * HH + gcol];
      }
    }
    bar_sync(flags, ++ep, tid);
  }
#pragma unroll
  for (int rg = 0; rg < 4; ++rg) hF[(crow + rg) * HH + gcol] = hfr[rg];
}

// -------- normalize pass: sum 500 per-row partials, scale row (exp already stored) --------
__global__ __launch_bounds__(256) void k_softmax(float* __restrict__ out,
                                                 const float* __restrict__ Pp) {
  float* row = out + (size_t)blockIdx.x * VV;
  const float* pp = Pp + (size_t)blockIdx.x * 512;
  const int tid = threadIdx.x;
  __shared__ float red[4];
  float sum = 0.f;
  for (int i = tid; i < 500; i += 256) sum += pp[i];
#pragma unroll
  for (int s = 32; s >= 1; s >>= 1) sum += __shfl_xor(sum, s);
  if ((tid & 63) == 0) red[tid >> 6] = sum;
  __syncthreads();
  float inv = 1.f / (red[0] + red[1] + red[2] + red[3]);
  for (int i = tid * 4; i < VV; i += 1024) {
    float4v v = *(const float4v*)(row + i);
    v[0] *= inv; v[1] *= inv; v[2] *= inv; v[3] *= inv;
    *(float4v*)(row + i) = v;
  }
}

extern "C" void kernel_launch(void* const* d_in, const int* in_sizes, int n_in,
                              void* d_out, int out_size, void* d_ws, size_t ws_size,
                              hipStream_t stream) {
  (void)in_sizes; (void)n_in; (void)out_size; (void)ws_size;
  const int*   enc  = (const int*)d_in[0];
  const int*   dec  = (const int*)d_in[1];
  const float* embF = (const float*)d_in[2];
  const float* Wd1  = (const float*)d_in[3];
  const float* bd1  = (const float*)d_in[4];
  const float* Wf1  = (const float*)d_in[5];
  const float* Uf1  = (const float*)d_in[6];
  const float* bf1  = (const float*)d_in[7];
  const float* Wf2  = (const float*)d_in[8];
  const float* Uf2  = (const float*)d_in[9];
  const float* bf2  = (const float*)d_in[10];
  const float* embE = (const float*)d_in[11];
  const float* We1  = (const float*)d_in[12];
  const float* Ue1  = (const float*)d_in[13];
  const float* be1  = (const float*)d_in[14];
  const float* We2  = (const float*)d_in[15];
  const float* Ue2  = (const float*)d_in[16];
  const float* be2  = (const float*)d_in[17];
  const float* Wout = (const float*)d_in[18];
  const float* bout = (const float*)d_in[19];

  char* p = (char*)d_ws;
  auto alloc = [&](size_t bytes) { char* r = p; p += (bytes + 255) & ~(size_t)255; return r; };
  short* WdT = (short*)alloc((size_t)896 * 800 * 2);
  short* WTb[4]; short* UTb[4];
  for (int i = 0; i < 4; ++i) {
    WTb[i] = (short*)alloc((size_t)2432 * 800 * 2);
    UTb[i] = (short*)alloc((size_t)2400 * 800 * 2);
  }
  short* WoT = (short*)alloc((size_t)VV * 800 * 2);
  short* feA = (short*)alloc((size_t)MR * DD * 2);
  short* fe  = (short*)alloc((size_t)MR * DD * 2);
  short* ee  = (short*)alloc((size_t)MR * DD * 2);
  short* g1  = (short*)alloc((size_t)MR * HH * 2);
  short* g2s = (short*)alloc((size_t)MR * HH * 2);   // layer-1 hSeq scratch
  short* e1  = (short*)alloc((size_t)MR * HH * 2);
  short* e2  = (short*)alloc((size_t)MR * HH * 2);
  float* xg  = (float*)alloc((size_t)MR * N3H * 4);
  float* Ppart = (float*)alloc((size_t)MR * 512 * 4);
  float* Spart = (float*)alloc((size_t)TT * 50 * 128 * 4);
  // --- zeroed-at-launch region: hF .. flags ---
  float* hF   = (float*)alloc((size_t)BB * HH * 4);
  short* hIn0 = (short*)alloc((size_t)BB * HH * 2);
  int* flags  = (int*)alloc((size_t)NBLK * 32 * 4);

  size_t tail = (char*)(flags + NBLK * 32) - (char*)hF;
  hipMemsetAsync(hF, 0, tail, stream);

  dim3 tb(32, 8);
  k_cast_transpose<<<dim3(25, 25), tb, 0, stream>>>(Wd1, WdT, 800, 800);
  const float* Ws[4] = {Wf1, Wf2, We1, We2};
  const float* Us[4] = {Uf1, Uf2, Ue1, Ue2};
  for (int i = 0; i < 4; ++i) {
    k_cast_transpose<<<dim3(75, 25), tb, 0, stream>>>(Ws[i], WTb[i], 800, 2400);
    k_cast_transpose<<<dim3(75, 25), tb, 0, stream>>>(Us[i], UTb[i], 800, 2400);
  }
  k_cast_transpose<<<dim3(1000, 25), tb, 0, stream>>>(Wout, WoT, 800, VV);
  k_gather<<<MR, 128, 0, stream>>>(enc, embF, feA);
  k_gather<<<MR, 128, 0, stream>>>(dec, embE, ee);
  // fe = relu(feA @ Wd1 + bd1)  -> bf16
  k_gemm<1><<<dim3(7, 24), 256, 0, stream>>>(feA, WdT, bd1, nullptr, fe, nullptr, 800, 800, 800);

  const float* bs[4] = {bf1, bf2, be1, be2};
  const short* Xs[4] = {fe, g1, ee, e1};
  short* hSeqL[4] = {g1, g2s, e1, e2};
  for (int l = 0; l < 4; ++l) {
    const short* hInit = (l == 0) ? hIn0 : hSeqL[l - 1] + (size_t)(TT - 1) * BB * HH;
    k_gemm<0><<<dim3(19, 24), 256, 0, stream>>>(Xs[l], WTb[l], bs[l], xg, nullptr, nullptr, N3H, 800, N3H);
    k_scan<<<NBLK, 512, 0, stream>>>(xg, UTb[l], bs[l] + N3H, hF, hInit, hSeqL[l],
                                     Spart, flags, l * 2 * TT);
  }
  // out = exp(e2 @ Wout + bout) -> d_out (row-permuted to [B,T,V]) + row partials
  k_gemm<2><<<dim3(250, 24), 256, 0, stream>>>(e2, WoT, bout, (float*)d_out, nullptr, Ppart, VV, 800, VV);
  k_softmax<<<MR, 256, 0, stream>>>((float*)d_out, Ppart);
}